// Round 13
// baseline (185.350 us; speedup 1.0000x reference)
//
#include <hip/hip_runtime.h>

#define BB 64
#define CC 512
#define NPIX 784
#define KK 32
#define NSA 13          // kA: 13 splits of 64 px (split 12 overlaps: p0=720)
#define AS 800          // A row stride in shorts (784 padded to 25*32)
#define CW_S 520        // cw LDS row stride (shorts): conflict-free b128 reads
#define NSTEP 24        // kB full 32-wide n-steps (24*32 = 768), +1 predicated tail

typedef __attribute__((ext_vector_type(8))) short short8;
typedef __attribute__((ext_vector_type(4))) float floatx4;
typedef __attribute__((ext_vector_type(16))) float floatx16;
typedef __attribute__((ext_vector_type(4))) unsigned short ushort4v;

// workspace layout: A bf16 [64][32][800] (3.28 MB), then wsum_p fp32 [13][64][32]
#define WSUM_OFF (BB * KK * AS)   // in shorts; byte offset 3,276,800 (16-aligned)

__device__ __forceinline__ unsigned short f2bf(float f) {
    union { float f; unsigned u; } v; v.f = f;
    return (unsigned short)((v.u + 0x7FFFu + ((v.u >> 16) & 1u)) >> 16);
}
__device__ __forceinline__ float bf2f(unsigned short h) {
    union { unsigned u; float f; } v; v.u = ((unsigned)h) << 16; return v.f;
}
__device__ __forceinline__ short8 pack8(const float4& a, const float4& b) {
    short8 r;
    r[0] = (short)f2bf(a.x); r[1] = (short)f2bf(a.y);
    r[2] = (short)f2bf(a.z); r[3] = (short)f2bf(a.w);
    r[4] = (short)f2bf(b.x); r[5] = (short)f2bf(b.y);
    r[6] = (short)f2bf(b.z); r[7] = (short)f2bf(b.w);
    return r;
}

// ---------------------------------------------------------------------------
// kA: per (64-px split, batch): A[k][px] = softmax_k(scale_k*(xsq+csq_k-2 x.c_k))
//  - 32x32x16 MFMA, 32-px waves -> 128 B x-load segments (r12's proven
//    per-wave-efficiency doubler) COMBINED WITH r3's TLP (13 waves/CU):
//    each wave contracts only C/2=256 (16 kc-steps), block = 2 px-tiles x
//    2 C-halves, grid 13x64 = 832 blocks.
//  - same register va/vb double-buffer, zero barriers in main loop.
//  - 2-way partial acc combine via LDS (stride-20 rows: <=8-way, one-time);
//    epilogue = r12's verified 32x32 softmax, run by ch==0 wave per tile.
//  - split 12 (p0=720): A-writes idempotent dups; wsum counts only px>=768.
// ---------------------------------------------------------------------------
__global__ __launch_bounds__(256, 3) void kA(const float* __restrict__ x,
                                             const float* __restrict__ cw,
                                             const float* __restrict__ scale,
                                             unsigned short* __restrict__ Ag)
{
    __shared__ __align__(16) unsigned short cs[KK * CW_S];   // 33280 B
    __shared__ __align__(16) float accr[2][64][20];          // 10240 B (acc16 + xsq @16)
    __shared__ float csq_p[8][KK];
    __shared__ float csq_l[KK];
    __shared__ float wredA[2][KK];

    const int t    = threadIdx.x;
    const int lane = t & 63, w = t >> 6;
    const int pl   = lane & 31, h = lane >> 5;
    const int tile = w & 1, ch = w >> 1;
    const int split = blockIdx.x, b = blockIdx.y;
    const int p0    = (split < 12) ? split * 64 : 720;   // split 12 overlaps by 48 px

    // ---- zero A pad region n in [784,800) once per batch (idempotent) ----
    if (split == 0 && t < 64) {
        const short8 z = {0, 0, 0, 0, 0, 0, 0, 0};
        const int k = t >> 1, off = (t & 1) * 8;
        *(short8*)&Ag[(size_t)b * KK * AS + (size_t)k * AS + NPIX + off] = z;
    }

    // ---- stage cw -> bf16 LDS ----
#pragma unroll 4
    for (int j = 0; j < 16; ++j) {
        const int qidx = t + j * 256;
        const int row = qidx >> 7, qc = qidx & 127;
        const float4 v = *(const float4*)&cw[row * CC + qc * 4];
        ushort4v p; p.x = f2bf(v.x); p.y = f2bf(v.y); p.z = f2bf(v.z); p.w = f2bf(v.w);
        *(ushort4v*)&cs[row * CW_S + qc * 4] = p;
    }
    __syncthreads();
    // ---- csq ----
    {
        const int k = t & 31, part = t >> 5;
        float s = 0.f;
        for (int i = 0; i < 64; ++i) {
            const float v = bf2f(cs[k * CW_S + part * 64 + i]);
            s += v * v;
        }
        csq_p[part][k] = s;
    }
    __syncthreads();
    if (t < KK) {
        float s = 0.f;
#pragma unroll
        for (int p = 0; p < 8; ++p) s += csq_p[p][t];
        csq_l[t] = s;
    }
    __syncthreads();

    const float sk = scale[pl];      // k = pl
    const float qk = csq_l[pl];

    // ---- main MFMA: wave (tile, ch): px-tile [p0+tile*32,+32), c in [ch*256,+256) ----
    const int px = p0 + tile * 32 + pl;
    const float* xb = x + (size_t)b * CC * NPIX + px;
    const int cbase = ch * 256;

    floatx16 acc = {0.f,0.f,0.f,0.f,0.f,0.f,0.f,0.f,0.f,0.f,0.f,0.f,0.f,0.f,0.f,0.f};
    float xsqp = 0.f;
    float va[8], vb[8];

#pragma unroll
    for (int j = 0; j < 8; ++j) va[j] = xb[(size_t)(cbase + h * 8 + j) * NPIX];

#pragma unroll
    for (int kc = 0; kc < 16; kc += 2) {
        // prefetch kc+1 into vb
        {
            const int cb = cbase + (kc + 1) * 16 + h * 8;
#pragma unroll
            for (int j = 0; j < 8; ++j) vb[j] = xb[(size_t)(cb + j) * NPIX];
        }
        // process va (kc)
        {
            short8 a;
#pragma unroll
            for (int j = 0; j < 8; ++j) { xsqp += va[j] * va[j]; a[j] = (short)f2bf(va[j]); }
            const short8 bf = *(const short8*)&cs[pl * CW_S + cbase + kc * 16 + h * 8];
            acc = __builtin_amdgcn_mfma_f32_32x32x16_bf16(a, bf, acc, 0, 0, 0);
        }
        // prefetch kc+2 into va
        if (kc + 2 < 16) {
            const int cb = cbase + (kc + 2) * 16 + h * 8;
#pragma unroll
            for (int j = 0; j < 8; ++j) va[j] = xb[(size_t)(cb + j) * NPIX];
        }
        // process vb (kc+1)
        {
            short8 a;
#pragma unroll
            for (int j = 0; j < 8; ++j) { xsqp += vb[j] * vb[j]; a[j] = (short)f2bf(vb[j]); }
            const short8 bf = *(const short8*)&cs[pl * CW_S + cbase + (kc + 1) * 16 + h * 8];
            acc = __builtin_amdgcn_mfma_f32_32x32x16_bf16(a, bf, acc, 0, 0, 0);
        }
    }

    // wave's C-half xsq for px=pl (combine h halves)
    const float xsqh = xsqp + __shfl_xor(xsqp, 32);

    // ---- 2-way C-half combine via LDS ----
    if (ch == 1) {
#pragma unroll
        for (int q = 0; q < 4; ++q)
            *(floatx4*)&accr[tile][lane][q * 4] =
                (floatx4){acc[q*4], acc[q*4+1], acc[q*4+2], acc[q*4+3]};
        accr[tile][lane][16] = xsqh;
    }
    __syncthreads();

    if (ch == 0) {
#pragma unroll
        for (int r = 0; r < 16; ++r) acc[r] += accr[tile][lane][r];
        const float xsqf = xsqh + accr[tile][lane][16];

        // fused softmax epilogue; D: col=pl=k, row(px in tile)=(r&3)+8*(r>>2)+4*h
        unsigned short* Ab = Ag + (size_t)b * KK * AS + p0 + tile * 32;
        float ts = 0.f;   // per-lane wsum partial for k=pl
#pragma unroll
        for (int r = 0; r < 16; ++r) {
            const int pwr = (r & 3) + 8 * (r >> 2) + 4 * h;   // px within tile
            const float xq = __shfl(xsqf, pwr);               // lane pwr holds that px's xsq
            const float d = sk * (xq + qk - 2.f * acc[r]);
            float mx = d;
            mx = fmaxf(mx, __shfl_xor(mx, 1));
            mx = fmaxf(mx, __shfl_xor(mx, 2));
            mx = fmaxf(mx, __shfl_xor(mx, 4));
            mx = fmaxf(mx, __shfl_xor(mx, 8));
            mx = fmaxf(mx, __shfl_xor(mx, 16));
            const float e = __expf(d - mx);
            float sm = e;
            sm += __shfl_xor(sm, 1);
            sm += __shfl_xor(sm, 2);
            sm += __shfl_xor(sm, 4);
            sm += __shfl_xor(sm, 8);
            sm += __shfl_xor(sm, 16);
            const float av = e * (1.f / sm);
            Ab[pl * AS + pwr] = f2bf(av);
            // wsum: split 12 counts only new px (>=768: tile 1, pwr>=16 i.e. r>=8)
            if (split < 12) ts += av;
            else if (tile == 1 && r >= 8) ts += av;
        }
        ts += __shfl_xor(ts, 32);
        if (lane < 32) wredA[tile][pl] = ts;
    }
    __syncthreads();
    if (t < KK) {
        const float s = wredA[0][t] + wredA[1][t];
        float* wsf = (float*)(Ag + WSUM_OFF);
        wsf[(size_t)(split * BB + b) * KK + t] = s;
    }
}

// ---------------------------------------------------------------------------
// kB: per (c-chunk of 64, batch): out[k][c] = sum_n A[k][n] x[c][n] - wsum_k cw[k][c]
//  - barrier-free main loop, A (L2-hot) and x (L3-hot from kA) direct from global
//  - wsum from kA's per-split partials (13 adds per k)
// ---------------------------------------------------------------------------
__global__ __launch_bounds__(256) void kB(const float* __restrict__ x,
                                          const float* __restrict__ cw,
                                          const unsigned short* __restrict__ Ag,
                                          float* __restrict__ out)
{
    __shared__ float wsum_l[KK];

    const int t    = threadIdx.x;
    const int lane = t & 63, w = t >> 6;
    const int col  = lane & 15, quad = lane >> 4;
    const int cch  = blockIdx.x, b = blockIdx.y;

    const unsigned short* Ab = Ag + (size_t)b * KK * AS;

    // ---- wsum: sum kA's 13 per-split partials ----
    if (t < KK) {
        const float* wsf = (const float*)(Ag + WSUM_OFF);
        float s = 0.f;
#pragma unroll
        for (int sp = 0; sp < NSA; ++sp) s += wsf[(size_t)(sp * BB + b) * KK + t];
        wsum_l[t] = s;
    }

    // ---- main GEMM: this wave owns 16 c-rows; contract n = 0..800 ----
    const int c = cch * 64 + w * 16 + col;
    const float* xp = x + ((size_t)b * CC + c) * NPIX;
    const unsigned short* a0p = Ab + (size_t)col * AS;
    const unsigned short* a1p = Ab + (size_t)(col + 16) * AS;
    const int qo = quad * 8;

    floatx4 acc0 = {0.f, 0.f, 0.f, 0.f};
    floatx4 acc1 = {0.f, 0.f, 0.f, 0.f};
#pragma unroll 6
    for (int s = 0; s < NSTEP; ++s) {
        const int off = s * 32 + qo;
        const short8 av0 = *(const short8*)&a0p[off];
        const short8 av1 = *(const short8*)&a1p[off];
        const float4 xv0 = *(const float4*)&xp[off];
        const float4 xv1 = *(const float4*)&xp[off + 4];
        const short8 bv = pack8(xv0, xv1);
        acc0 = __builtin_amdgcn_mfma_f32_16x16x32_bf16(av0, bv, acc0, 0, 0, 0);
        acc1 = __builtin_amdgcn_mfma_f32_16x16x32_bf16(av1, bv, acc1, 0, 0, 0);
    }
    {   // tail step: n in [768,800); x rows end at 784 -> predicate quads 2,3 (A pad is zero)
        const int off = NSTEP * 32 + qo;
        const short8 av0 = *(const short8*)&a0p[off];
        const short8 av1 = *(const short8*)&a1p[off];
        float4 xv0 = make_float4(0.f, 0.f, 0.f, 0.f);
        float4 xv1 = make_float4(0.f, 0.f, 0.f, 0.f);
        if (quad < 2) {
            xv0 = *(const float4*)&xp[off];
            xv1 = *(const float4*)&xp[off + 4];
        }
        const short8 bv = pack8(xv0, xv1);
        acc0 = __builtin_amdgcn_mfma_f32_16x16x32_bf16(av0, bv, acc0, 0, 0, 0);
        acc1 = __builtin_amdgcn_mfma_f32_16x16x32_bf16(av1, bv, acc1, 0, 0, 0);
    }

    __syncthreads();   // wsum_l ready

    // ---- fused epilogue: out = W - wsum*cw ----
    float* ob = out + (size_t)b * KK * CC + c;
    const float* cp = cw + c;
#pragma unroll
    for (int r = 0; r < 4; ++r) {
        const int k0 = quad * 4 + r;
        ob[(size_t)k0 * CC]        = acc0[r] - wsum_l[k0]      * cp[(size_t)k0 * CC];
        ob[(size_t)(k0 + 16) * CC] = acc1[r] - wsum_l[k0 + 16] * cp[(size_t)(k0 + 16) * CC];
    }
}

extern "C" void kernel_launch(void* const* d_in, const int* in_sizes, int n_in,
                              void* d_out, int out_size, void* d_ws, size_t ws_size,
                              hipStream_t stream) {
    const float* x     = (const float*)d_in[0];   // (64, 512, 28, 28)
    const float* cw    = (const float*)d_in[1];   // (32, 512)
    const float* scale = (const float*)d_in[2];   // (32,)
    float* out = (float*)d_out;                   // (64, 32, 512)
    unsigned short* Ag = (unsigned short*)d_ws;   // A bf16 [64][32][800] + wsum_p f32 [13][64][32]

    kA<<<dim3(NSA, BB), dim3(256), 0, stream>>>(x, cw, scale, Ag);
    kB<<<dim3(8, BB), dim3(256), 0, stream>>>(x, cw, Ag, out);
}